// Round 10
// baseline (1541.245 us; speedup 1.0000x reference)
//
#include <hip/hip_runtime.h>

namespace {

constexpr int NBATCH = 2048;
constexpr int NT     = 200;

typedef __bf16 bf16x8 __attribute__((ext_vector_type(8)));
typedef float  f32x16 __attribute__((ext_vector_type(16)));

struct Frag3 { bf16x8 h, m, l; };

// Exact 3-way split of fp32 into bf16 hi/mid/lo. Hi stage: manual RTNE
// (proven R4/R7). Mid/lo: hardware __bf16 cvt; residuals r1 = v - hi,
// r2 = r1 - mid remain exact in fp32. hi+mid+lo ~ v to 2^-24. (proven R8)
__device__ inline Frag3 split3_8(const float f[8]) {
  Frag3 r;
  #pragma unroll
  for (int e = 0; e < 8; ++e) {
    const float v = f[e];
    unsigned int hb = __float_as_uint(v);
    hb += 0x7FFFu + ((hb >> 16) & 1u);       // RTNE to bf16 (manual, proven)
    hb &= 0xFFFF0000u;
    const float hf = __uint_as_float(hb);
    const float r1 = v - hf;                 // exact
    const __bf16 mB = (__bf16)r1;            // hw RTNE cvt
    const float r2 = r1 - (float)mB;         // exact
    const __bf16 lB = (__bf16)r2;
    r.h[e] = (__bf16)hf;                     // exact (hf is bf16-representable)
    r.m[e] = mB;
    r.l[e] = lB;
  }
  return r;
}

// Cross-term group (lh, hl, mm, mh, hm) — accumulate separately from hh so
// all rounding happens at ulp(2^-7|D|). Merge in fp32 VALU afterwards.
__device__ inline f32x16 mm_lo(f32x16 acc, const Frag3& a, const Frag3& b) {
  acc = __builtin_amdgcn_mfma_f32_32x32x16_bf16(a.l, b.h, acc, 0, 0, 0);
  acc = __builtin_amdgcn_mfma_f32_32x32x16_bf16(a.h, b.l, acc, 0, 0, 0);
  acc = __builtin_amdgcn_mfma_f32_32x32x16_bf16(a.m, b.m, acc, 0, 0, 0);
  acc = __builtin_amdgcn_mfma_f32_32x32x16_bf16(a.m, b.h, acc, 0, 0, 0);
  acc = __builtin_amdgcn_mfma_f32_32x32x16_bf16(a.h, b.m, acc, 0, 0, 0);
  return acc;
}
__device__ inline f32x16 mm_hh(f32x16 acc, const Frag3& a, const Frag3& b) {
  return __builtin_amdgcn_mfma_f32_32x32x16_bf16(a.h, b.h, acc, 0, 0, 0);
}

// C/D-layout regs -> B-operand Frag3 pair. One half-exchange via
// shfl_xor(32), then select + split. (R8-proven path)
__device__ inline void cd_to_bfrag(const f32x16 cd, const int up, Frag3 out[2]) {
  float sw[16];
  #pragma unroll
  for (int r = 0; r < 16; ++r) sw[r] = __shfl_xor(cd[r], 32, 64);
  #pragma unroll
  for (int h = 0; h < 2; ++h) {
    float f[8];
    const int base = 8 * h;
    #pragma unroll
    for (int e = 0; e < 4; ++e) {
      f[e]     = up ? sw[base + 4 + e] : cd[base + e];
      f[4 + e] = up ? cd[base + 4 + e] : sw[base + e];
    }
    out[h] = split3_8(f);
  }
}

// Precompute QG[b][t][j] = (Q_b * goal_t)[j] for t = 0..200.
// Same ascending-m FMA chain as the in-loop version -> bit-identical.
__global__ __launch_bounds__(64) void qg_kernel(
    const float* __restrict__ gQ, const float* __restrict__ gG,
    float* __restrict__ QG)
{
    __shared__ float sQ[1024];
    const int lane = threadIdx.x;
    const int b    = blockIdx.x;
    const float* __restrict__ Qb = gQ + (size_t)b * 1024;
    const float* __restrict__ Gb = gG + (size_t)b * (201 * 32);
    float* __restrict__ QGb = QG + (size_t)b * (201 * 32);
    #pragma unroll
    for (int m = 0; m < 4; ++m)
        reinterpret_cast<float4*>(sQ)[lane + 64 * m] =
            reinterpret_cast<const float4*>(Qb)[lane + 64 * m];
    const int jj = lane & 31, th = lane >> 5;
    for (int t = th; t < 201; t += 2) {
        const float* __restrict__ g = Gb + t * 32;
        float acc = 0.f;
        #pragma unroll
        for (int m = 0; m < 32; ++m) acc += sQ[m * 32 + jj] * g[m];
        QGb[t * 32 + jj] = acc;
    }
}

// Per-chain state: one batch element's recursion. Two chains live in one
// wave (independent dependency graphs -> the scheduler fills each chain's
// stalls with the other's instructions).
struct Chain {
    float *sA, *sQ, *sAt, *sBp, *sBtV, *sM2, *svv, *sbtv;  // LDS slices
    const float* Gb;
    const float* qgp;
    Frag3 AtF[2];   // A-frag of A^T AND B-frag of A
    Frag3 BtF[2];   // B^T zero-padded, A-frag
    Frag3 BFa;      // B as A-operand (K=16 tile)
    f32x16 afr, qfr, vacc;
    float rreg;
    int b;
};

constexpr int CH_STRIDE = 4104;   // floats per chain LDS slice

template <bool USE_QG>
__device__ inline void chain_init(Chain& C, const int b, const int lane,
    const int up, const int col, const int jj,
    const float* __restrict__ gA, const float* __restrict__ gB,
    const float* __restrict__ gQ, const float* __restrict__ gR,
    const float* __restrict__ gG, const float* __restrict__ gQG,
    float* __restrict__ lds)
{
    C.b    = b;
    C.sA   = lds;          // [32][32]
    C.sQ   = lds + 1024;   // [32][32] (fallback only)
    C.sAt  = lds + 2048;   // [32][36] A^T padded
    C.sBp  = lds + 3200;   // [32][9]
    C.sBtV = lds + 3488;   // [8][36]; aliased as Kg later
    C.sM2  = lds + 3776;   // [8][36]
    C.svv  = lds + 4064;   // [32]
    C.sbtv = lds + 4096;   // [8]

    const float* __restrict__ Ab = gA + (size_t)b * 1024;
    const float* __restrict__ Bb = gB + (size_t)b * 256;
    const float* __restrict__ Qb = gQ + (size_t)b * 1024;
    C.Gb = gG + (size_t)b * (201 * 32);
    const float* __restrict__ QGb = USE_QG ? gQG + (size_t)b * (201 * 32) : nullptr;

    #pragma unroll
    for (int m = 0; m < 4; ++m)
        reinterpret_cast<float4*>(C.sA)[lane + 64 * m] =
            reinterpret_cast<const float4*>(Ab)[lane + 64 * m];
    if constexpr (!USE_QG) {
        #pragma unroll
        for (int m = 0; m < 4; ++m)
            reinterpret_cast<float4*>(C.sQ)[lane + 64 * m] =
                reinterpret_cast<const float4*>(Qb)[lane + 64 * m];
    }
    // A^T tile for the v' row-major b128 reads
    #pragma unroll
    for (int t = 0; t < 16; ++t) {
        const int mm = 2 * t + up;
        C.sAt[col * 36 + mm] = Ab[mm * 32 + col];
    }
    {
        float4 b4 = reinterpret_cast<const float4*>(Bb)[lane];
        const int fb = lane * 4;
        C.sBp[((fb + 0) >> 3) * 9 + ((fb + 0) & 7)] = b4.x;
        C.sBp[((fb + 1) >> 3) * 9 + ((fb + 1) & 7)] = b4.y;
        C.sBp[((fb + 2) >> 3) * 9 + ((fb + 2) & 7)] = b4.z;
        C.sBp[((fb + 3) >> 3) * 9 + ((fb + 3) & 7)] = b4.w;
    }
    C.rreg = gR[(size_t)b * 64 + lane];   // R[ig][kg]

    #pragma unroll
    for (int h = 0; h < 2; ++h) {
        float f[8];
        #pragma unroll
        for (int e = 0; e < 8; ++e) f[e] = Ab[(16 * h + 8 * up + e) * 32 + col];
        C.AtF[h] = split3_8(f);
    }
    #pragma unroll
    for (int h = 0; h < 2; ++h) {
        float f[8];
        #pragma unroll
        for (int e = 0; e < 8; ++e)
            f[e] = (col < 8) ? Bb[(16 * h + 8 * up + e) * 8 + col] : 0.f;
        C.BtF[h] = split3_8(f);
    }
    {
        float f[8];
        #pragma unroll
        for (int e = 0; e < 8; ++e) f[e] = up ? 0.f : Bb[col * 8 + e];
        C.BFa = split3_8(f);
    }
    #pragma unroll
    for (int r = 0; r < 16; ++r) {
        const int row = (r & 3) + 8 * (r >> 2) + 4 * up;
        C.afr[r] = Ab[row * 32 + col];
        C.qfr[r] = Qb[row * 32 + col];
    }

    // v0 = Q * goals[:, T, :]
    if constexpr (USE_QG) {
        if (lane < 32) C.svv[jj] = QGb[200 * 32 + jj];
        C.qgp = QGb + 199 * 32;
    } else {
        const float* __restrict__ gl = C.Gb + 200 * 32;
        float t = 0.f;
        #pragma unroll
        for (int m = 0; m < 32; ++m) t += C.sQ[m * 32 + jj] * gl[m];
        if (lane < 32) C.svv[jj] = t;
        C.qgp = nullptr;
    }
    C.vacc = C.qfr;   // V0 = Q
}

// ---- per-phase helpers (bodies identical to R8) ----

__device__ inline void mfma_p1(const Chain& C, const Frag3 VF[2],
                               f32x16& bacc, f32x16& pC, f32x16& pB)
{
    #pragma unroll
    for (int r = 0; r < 16; ++r) { bacc[r] = 0.f; pC[r] = 0.f; pB[r] = 0.f; }
    bacc = mm_lo(bacc, C.BtF[0], VF[0]);
    bacc = mm_lo(bacc, C.BtF[1], VF[1]);
    bacc = mm_hh(bacc, C.BtF[0], VF[0]);
    bacc = mm_hh(bacc, C.BtF[1], VF[1]);
    pC = mm_lo(pC, VF[0], C.AtF[0]);
    pC = mm_lo(pC, VF[1], C.AtF[1]);
    pB = mm_hh(pB, VF[0], C.AtF[0]);
    pB = mm_hh(pB, VF[1], C.AtF[1]);
}

__device__ inline void btv_phase(const Chain& C, const int lane) {
    const int u = lane & 7, q8 = lane >> 3;
    const float4 v4 = *reinterpret_cast<const float4*>(&C.svv[4 * q8]);
    float p = 0.f;
    p += C.sBp[(4 * q8 + 0) * 9 + u] * v4.x;
    p += C.sBp[(4 * q8 + 1) * 9 + u] * v4.y;
    p += C.sBp[(4 * q8 + 2) * 9 + u] * v4.z;
    p += C.sBp[(4 * q8 + 3) * 9 + u] * v4.w;
    p += __shfl_xor(p, 8, 64);
    p += __shfl_xor(p, 16, 64);
    p += __shfl_xor(p, 32, 64);
    if (lane < 8) C.sbtv[u] = p;
}

__device__ inline void vuu_m2(const Chain& C, const f32x16 bacc,
                              const int up, const int col, const int ig,
                              const int kg, const int k0,
                              float& cur, float& cur8)
{
    #pragma unroll
    for (int q = 0; q < 4; ++q)
        C.sBtV[(q + 4 * up) * 36 + col] = bacc[q];
    float m20 = 0, m21 = 0, m22 = 0, m23 = 0, vu = C.rreg;
    #pragma unroll
    for (int jb = 0; jb < 8; ++jb) {
        const float4 bt4 = *reinterpret_cast<const float4*>(&C.sBtV[ig * 36 + 4 * jb]);
        #pragma unroll
        for (int q = 0; q < 4; ++q) {
            const int j = 4 * jb + q;
            const float btvj = (q == 0) ? bt4.x : (q == 1) ? bt4.y
                             : (q == 2) ? bt4.z : bt4.w;
            const float4 a4 = *reinterpret_cast<const float4*>(&C.sA[j * 32 + k0]);
            const float  bk = C.sBp[j * 9 + kg];
            m20 += btvj * a4.x; m21 += btvj * a4.y;
            m22 += btvj * a4.z; m23 += btvj * a4.w;
            vu  += btvj * bk;
        }
    }
    *reinterpret_cast<float4*>(&C.sM2[ig * 36 + k0]) = make_float4(m20, m21, m22, m23);
    cur  = vu;
    cur8 = (ig == kg) ? 1.f : 0.f;
}

__device__ inline void p3_phase(const Chain& C, const float cur8,
                                const int ig, const int kg, const int k0,
                                const int step,
                                float* __restrict__ outK,
                                float* __restrict__ outk)
{
    float* const sKg = C.sBtV;   // BtV dead after the fused loop
    float ka0 = 0, ka1 = 0, ka2 = 0, ka3 = 0, kfv = 0;
    #pragma unroll
    for (int u2 = 0; u2 < 8; ++u2) {
        const float  w  = __shfl(cur8, ig * 8 + u2, 64);   // inv[ig][u2]
        const float4 m4 = *reinterpret_cast<const float4*>(&C.sM2[u2 * 36 + k0]);
        const float  bt = C.sbtv[u2];
        ka0 += w * m4.x; ka1 += w * m4.y; ka2 += w * m4.z; ka3 += w * m4.w;
        kfv += w * bt;
    }
    *reinterpret_cast<float4*>(&sKg[ig * 36 + k0]) = make_float4(ka0, ka1, ka2, ka3);
    const size_t ob = (size_t)step * NBATCH + C.b;
    *reinterpret_cast<float4*>(&outK[ob * 256 + ig * 32 + k0]) =
        make_float4(ka0, ka1, ka2, ka3);
    if (kg == 0) outk[ob * 8 + ig] = kfv;
}

__device__ inline Frag3 kg_frag(const Chain& C, const int up, const int col) {
    float fk[8];
    #pragma unroll
    for (int e = 0; e < 8; ++e)
        fk[e] = up ? 0.f : C.sBtV[e * 36 + col];   // sKg alias
    return split3_8(fk);
}

__device__ inline f32x16 abk_calc(const Chain& C, const Frag3& KgF) {
    f32x16 bkC, bkB;
    #pragma unroll
    for (int r = 0; r < 16; ++r) { bkC[r] = 0.f; bkB[r] = 0.f; }
    bkC = mm_lo(bkC, C.BFa, KgF);
    bkB = mm_hh(bkB, C.BFa, KgF);
    f32x16 abk;
    #pragma unroll
    for (int r = 0; r < 16; ++r) abk[r] = C.afr[r] - (bkC[r] + bkB[r]);
    return abk;
}

__device__ inline void vprime(const Frag3 PF[2], const Frag3 KF[2],
                              f32x16& vC, f32x16& vB)
{
    #pragma unroll
    for (int r = 0; r < 16; ++r) { vC[r] = 0.f; vB[r] = 0.f; }
    vC = mm_lo(vC, PF[0], KF[0]);
    vC = mm_lo(vC, PF[1], KF[1]);
    vB = mm_hh(vB, PF[0], KF[0]);
    vB = mm_hh(vB, PF[1], KF[1]);
}

__device__ inline void vvec_update(const Chain& C, const float t2,
                                   const int lane, const int jj)
{
    float t1 = 0.f;
    #pragma unroll
    for (int kb = 0; kb < 8; ++kb) {
        const float4 a4 = *reinterpret_cast<const float4*>(&C.sAt[jj * 36 + 4 * kb]);
        const float4 v4 = *reinterpret_cast<const float4*>(&C.svv[4 * kb]);
        t1 += a4.x * v4.x; t1 += a4.y * v4.y;
        t1 += a4.z * v4.z; t1 += a4.w * v4.w;
    }
    float tk = 0.f;
    #pragma unroll
    for (int u = 0; u < 8; ++u) tk += C.sBtV[u * 36 + jj] * C.sbtv[u];  // sKg alias
    if (lane < 32) C.svv[jj] = (t1 - tk) + t2;
}

// Two batch elements per wave (grid = NBATCH/2, 1 wave/SIMD, VGPR budget 512).
// Per-chain algebra/order is bit-identical to R8; the two chains' instruction
// streams interleave to fill each other's dependency stalls.
template <bool USE_QG>
__global__ __launch_bounds__(64, 1) void lqr_kernel(
    const float* __restrict__ gA, const float* __restrict__ gB,
    const float* __restrict__ gQ, const float* __restrict__ gR,
    const float* __restrict__ gG, const float* __restrict__ gQG,
    float* __restrict__ outK, float* __restrict__ outk)
{
    __shared__ __attribute__((aligned(16))) float smem[2 * CH_STRIDE];

    const int lane = threadIdx.x;
    const int ig   = lane >> 3;
    const int kg   = lane & 7;
    const int k0   = kg << 2;
    const int jj   = lane & 31;
    const int col  = lane & 31;
    const int up   = lane >> 5;

    Chain S0, S1;
    chain_init<USE_QG>(S0, 2 * blockIdx.x,     lane, up, col, jj,
                       gA, gB, gQ, gR, gG, gQG, smem);
    chain_init<USE_QG>(S1, 2 * blockIdx.x + 1, lane, up, col, jj,
                       gA, gB, gQ, gR, gG, gQG, smem + CH_STRIDE);

    for (int c = 0; c < NT; ++c) {
        const int step = NT - 1 - c;

        float t2_0, t2_1;
        if constexpr (USE_QG) {
            t2_0 = S0.qgp[jj];
            t2_1 = S1.qgp[jj];
        } else {
            const float* __restrict__ g0 = S0.Gb + step * 32;
            const float* __restrict__ g1 = S1.Gb + step * 32;
            t2_0 = 0.f; t2_1 = 0.f;
            #pragma unroll
            for (int m = 0; m < 32; ++m) {
                t2_0 += S0.sQ[m * 32 + jj] * g0[m];
                t2_1 += S1.sQ[m * 32 + jj] * g1[m];
            }
        }

        Frag3 VF0[2], VF1[2];
        cd_to_bfrag(S0.vacc, up, VF0);
        cd_to_bfrag(S1.vacc, up, VF1);

        f32x16 bacc0, pC0, pB0, bacc1, pC1, pB1;
        mfma_p1(S0, VF0, bacc0, pC0, pB0);
        mfma_p1(S1, VF1, bacc1, pC1, pB1);

        btv_phase(S0, lane);
        btv_phase(S1, lane);

        float cur0, cur8_0, cur1, cur8_1;
        vuu_m2(S0, bacc0, up, col, ig, kg, k0, cur0, cur8_0);
        vuu_m2(S1, bacc1, up, col, ig, kg, k0, cur1, cur8_1);

        // Gauss-Jordan, both chains interleaved (two serial shfl chains
        // overlap). PD with diag>=1 -> no pivoting. Math identical to R8.
        #pragma unroll
        for (int p = 0; p < 8; ++p) {
            const float piv0 = __shfl(cur0, p * 8 + p, 64);
            const float piv1 = __shfl(cur1, p * 8 + p, 64);
            const float rp0  = 1.0f / piv0;
            const float rp1  = 1.0f / piv1;
            const float pc0  = __shfl(cur0,   p * 8 + kg, 64);
            const float pc1  = __shfl(cur1,   p * 8 + kg, 64);
            const float pc80 = __shfl(cur8_0, p * 8 + kg, 64);
            const float pc81 = __shfl(cur8_1, p * 8 + kg, 64);
            const float mrp0 = __shfl(cur0,   ig * 8 + p, 64);
            const float mrp1 = __shfl(cur1,   ig * 8 + p, 64);
            const float f0 = mrp0 * rp0;
            const float f1 = mrp1 * rp1;
            const bool  isp = (ig == p);
            cur0   = isp ? pc0  * rp0 : cur0   - f0 * pc0;
            cur8_0 = isp ? pc80 * rp0 : cur8_0 - f0 * pc80;
            cur1   = isp ? pc1  * rp1 : cur1   - f1 * pc1;
            cur8_1 = isp ? pc81 * rp1 : cur8_1 - f1 * pc81;
        }

        f32x16 pM0, pM1;
        #pragma unroll
        for (int r = 0; r < 16; ++r) {
            pM0[r] = pC0[r] + pB0[r];
            pM1[r] = pC1[r] + pB1[r];
        }
        Frag3 PF0[2], PF1[2];
        cd_to_bfrag(pM0, up, PF0);
        cd_to_bfrag(pM1, up, PF1);

        p3_phase(S0, cur8_0, ig, kg, k0, step, outK, outk);
        p3_phase(S1, cur8_1, ig, kg, k0, step, outK, outk);

        const Frag3 KgF0 = kg_frag(S0, up, col);
        const Frag3 KgF1 = kg_frag(S1, up, col);
        const f32x16 abk0 = abk_calc(S0, KgF0);
        const f32x16 abk1 = abk_calc(S1, KgF1);
        Frag3 KF0[2], KF1[2];
        cd_to_bfrag(abk0, up, KF0);
        cd_to_bfrag(abk1, up, KF1);

        f32x16 vC0, vB0, vC1, vB1;
        vprime(PF0, KF0, vC0, vB0);
        vprime(PF1, KF1, vC1, vB1);

        vvec_update(S0, t2_0, lane, jj);
        vvec_update(S1, t2_1, lane, jj);

        #pragma unroll
        for (int r = 0; r < 16; ++r) {
            S0.vacc[r] = (vC0[r] + vB0[r]) + S0.qfr[r];
            S1.vacc[r] = (vC1[r] + vB1[r]) + S1.qfr[r];
        }

        if constexpr (USE_QG) { S0.qgp -= 32; S1.qgp -= 32; }
    }
}

}  // namespace

extern "C" void kernel_launch(void* const* d_in, const int* in_sizes, int n_in,
                              void* d_out, int out_size, void* d_ws, size_t ws_size,
                              hipStream_t stream) {
    const float* A = (const float*)d_in[0];
    const float* B = (const float*)d_in[1];
    const float* Q = (const float*)d_in[2];
    const float* R = (const float*)d_in[3];
    const float* G = (const float*)d_in[4];
    float* outK = (float*)d_out;
    float* outk = outK + (size_t)NT * NBATCH * 8 * 32;

    const size_t need = (size_t)NBATCH * 201 * 32 * sizeof(float);
    if (ws_size >= need) {
        float* QG = (float*)d_ws;
        qg_kernel<<<dim3(NBATCH), dim3(64), 0, stream>>>(Q, G, QG);
        lqr_kernel<true><<<dim3(NBATCH / 2), dim3(64), 0, stream>>>(
            A, B, Q, R, G, QG, outK, outk);
    } else {
        lqr_kernel<false><<<dim3(NBATCH / 2), dim3(64), 0, stream>>>(
            A, B, Q, R, G, nullptr, outK, outk);
    }
}

// Round 11
// 1122.099 us; speedup vs baseline: 1.3735x; 1.3735x over previous
//
#include <hip/hip_runtime.h>

namespace {

constexpr int NBATCH = 2048;
constexpr int NT     = 200;

typedef __bf16 bf16x8 __attribute__((ext_vector_type(8)));
typedef float  f32x16 __attribute__((ext_vector_type(16)));

struct Frag3 { bf16x8 h, m, l; };

// Exact 3-way split of fp32 into bf16 hi/mid/lo, all stages hardware RTNE
// casts (same rounding as the manual-RTNE version proven R4-R8; plain casts
// let the compiler fuse v_cvt_pk_bf16_f32 pairs). Residuals r1 = v - hi,
// r2 = r1 - mid are exact in fp32; hi+mid+lo represents v to ~2^-24 rel.
__device__ inline Frag3 split3_8(const float f[8]) {
  Frag3 r;
  #pragma unroll
  for (int e = 0; e < 8; ++e) {
    const float v = f[e];
    const __bf16 hB = (__bf16)v;             // RTNE
    const float r1 = v - (float)hB;          // exact (Sterbenz)
    const __bf16 mB = (__bf16)r1;            // RTNE
    const float r2 = r1 - (float)mB;         // exact
    r.h[e] = hB;
    r.m[e] = mB;
    r.l[e] = (__bf16)r2;
  }
  return r;
}

// Cross-term group (lh, hl, mm, mh, hm) — accumulate separately from hh so
// all rounding happens at ulp(2^-7|D|). Merge in fp32 VALU afterwards.
__device__ inline f32x16 mm_lo(f32x16 acc, const Frag3& a, const Frag3& b) {
  acc = __builtin_amdgcn_mfma_f32_32x32x16_bf16(a.l, b.h, acc, 0, 0, 0);
  acc = __builtin_amdgcn_mfma_f32_32x32x16_bf16(a.h, b.l, acc, 0, 0, 0);
  acc = __builtin_amdgcn_mfma_f32_32x32x16_bf16(a.m, b.m, acc, 0, 0, 0);
  acc = __builtin_amdgcn_mfma_f32_32x32x16_bf16(a.m, b.h, acc, 0, 0, 0);
  acc = __builtin_amdgcn_mfma_f32_32x32x16_bf16(a.h, b.m, acc, 0, 0, 0);
  return acc;
}
__device__ inline f32x16 mm_hh(f32x16 acc, const Frag3& a, const Frag3& b) {
  return __builtin_amdgcn_mfma_f32_32x32x16_bf16(a.h, b.h, acc, 0, 0, 0);
}

// C/D-layout regs -> B-operand Frag3 pair. One half-exchange via
// shfl_xor(32), then select + split. (R8-proven path)
__device__ inline void cd_to_bfrag(const f32x16 cd, const int up, Frag3 out[2]) {
  float sw[16];
  #pragma unroll
  for (int r = 0; r < 16; ++r) sw[r] = __shfl_xor(cd[r], 32, 64);
  #pragma unroll
  for (int h = 0; h < 2; ++h) {
    float f[8];
    const int base = 8 * h;
    #pragma unroll
    for (int e = 0; e < 4; ++e) {
      f[e]     = up ? sw[base + 4 + e] : cd[base + e];
      f[4 + e] = up ? cd[base + 4 + e] : sw[base + e];
    }
    out[h] = split3_8(f);
  }
}

// Precompute QG[b][t][j] = (Q_b * goal_t)[j] for t = 0..200.
// Same ascending-m FMA chain as the in-loop version -> bit-identical.
__global__ __launch_bounds__(64) void qg_kernel(
    const float* __restrict__ gQ, const float* __restrict__ gG,
    float* __restrict__ QG)
{
    __shared__ float sQ[1024];
    const int lane = threadIdx.x;
    const int b    = blockIdx.x;
    const float* __restrict__ Qb = gQ + (size_t)b * 1024;
    const float* __restrict__ Gb = gG + (size_t)b * (201 * 32);
    float* __restrict__ QGb = QG + (size_t)b * (201 * 32);
    #pragma unroll
    for (int m = 0; m < 4; ++m)
        reinterpret_cast<float4*>(sQ)[lane + 64 * m] =
            reinterpret_cast<const float4*>(Qb)[lane + 64 * m];
    const int jj = lane & 31, th = lane >> 5;
    for (int t = th; t < 201; t += 2) {
        const float* __restrict__ g = Gb + t * 32;
        float acc = 0.f;
        #pragma unroll
        for (int m = 0; m < 32; ++m) acc += sQ[m * 32 + jj] * g[m];
        QGb[t * 32 + jj] = acc;
    }
}

// One wave = one batch element, 200-step backward Riccati recursion.
// R4/R7-proven CONSISTENT algebra (every product consumes the same literal V~):
//   P   = V~^T A  (MFMA, VF-as-A-op) ; BtV = B^T V~ (MFMA) -> LDS
//   M2  = BtV * A (MFMA on the LITERAL LDS BtV; B-op = AtF reused)
//   Vuu = R + BtV*B (slim fp32 VALU loop) ; Kg = Vuu^-1 M2 (shfl GJ)
//   ABK = A - B*Kg (fp32 cancel FIRST)
//   V'  = P^T * ABK + Q (MFMA, PF-as-A-op = literal P^T = A^T V~)
//   v'  = A^T v - Kg^T (B^T v) + QG[step]
// MFMA 32x32x16_bf16 layouts (verified rounds 2-4):
//   A-frag: lane holds A'[l&31][16h + 8*(l>>5) + e]
//   B-frag: lane holds B'[16h + 8*(l>>5) + e][l&31]
//   C/D   : lane holds C[(r&3) + 8*(r>>2) + 4*(l>>5)][l&31]
template <bool USE_QG>
__global__ __launch_bounds__(64, 2) void lqr_kernel(
    const float* __restrict__ gA,   // [B,32,32]
    const float* __restrict__ gB,   // [B,32,8]
    const float* __restrict__ gQ,   // [B,32,32]
    const float* __restrict__ gR,   // [B,8,8]
    const float* __restrict__ gG,   // [B,201,32]
    const float* __restrict__ gQG,  // [B,201,32] precomputed Q*goal (or null)
    float* __restrict__ outK,       // [T,B,8,32]
    float* __restrict__ outk)       // [T,B,8]
{
    __shared__ __attribute__((aligned(16))) float smem[4104];
    float* const sA   = smem;          // [32][32] row-major
    float* const sQ   = smem + 1024;   // [32][32] (fallback Q*goal only)
    float* const sAt  = smem + 2048;   // [32][36] A^T, pad 36 (v' b128 rows)
    float* const sBp  = smem + 3200;   // [32][9]  B padded
    float* const sBtV = smem + 3488;   // [8][36]  B^T V ; aliased as Kg later
    float* const sM2  = smem + 3776;   // [8][36]  BtV*A
    float* const svv  = smem + 4064;   // [32] running v
    float* const sbtv = smem + 4096;   // [8]  B^T v

    const int lane = threadIdx.x;
    const int b    = blockIdx.x;
    const int ig   = lane >> 3;        // 0..7
    const int kg   = lane & 7;         // 0..7
    const int k0   = kg << 2;
    const int jj   = lane & 31;
    const int col  = lane & 31;        // MFMA col within tile
    const int up   = lane >> 5;        // 0/1: lane-half

    const float* __restrict__ Ab = gA + (size_t)b * 1024;
    const float* __restrict__ Bb = gB + (size_t)b * 256;
    const float* __restrict__ Qb = gQ + (size_t)b * 1024;
    const float* __restrict__ Gb = gG + (size_t)b * (201 * 32);
    const float* __restrict__ QGb = USE_QG ? gQG + (size_t)b * (201 * 32) : nullptr;

    // ---------------- one-time staging ----------------
    #pragma unroll
    for (int m = 0; m < 4; ++m)
        reinterpret_cast<float4*>(sA)[lane + 64 * m] =
            reinterpret_cast<const float4*>(Ab)[lane + 64 * m];
    if constexpr (!USE_QG) {
        #pragma unroll
        for (int m = 0; m < 4; ++m)
            reinterpret_cast<float4*>(sQ)[lane + 64 * m] =
                reinterpret_cast<const float4*>(Qb)[lane + 64 * m];
    }
    // A^T tile for the v' row-major b128 reads
    #pragma unroll
    for (int t = 0; t < 16; ++t) {
        const int mm = 2 * t + up;
        sAt[col * 36 + mm] = Ab[mm * 32 + col];
    }
    {
        float4 b4 = reinterpret_cast<const float4*>(Bb)[lane];
        const int fb = lane * 4;
        sBp[((fb + 0) >> 3) * 9 + ((fb + 0) & 7)] = b4.x;
        sBp[((fb + 1) >> 3) * 9 + ((fb + 1) & 7)] = b4.y;
        sBp[((fb + 2) >> 3) * 9 + ((fb + 2) & 7)] = b4.z;
        sBp[((fb + 3) >> 3) * 9 + ((fb + 3) & 7)] = b4.w;
    }
    const float rreg = gR[(size_t)b * 64 + lane];   // R[ig][kg]

    // AtF: A-frag of A^T AND B-frag of A (both read A[k][col]).
    Frag3 AtF[2];
    #pragma unroll
    for (int h = 0; h < 2; ++h) {
        float f[8];
        #pragma unroll
        for (int e = 0; e < 8; ++e) f[e] = Ab[(16 * h + 8 * up + e) * 32 + col];
        AtF[h] = split3_8(f);
    }
    // B^T zero-padded to 32x32 as A-frag
    Frag3 BtF[2];
    #pragma unroll
    for (int h = 0; h < 2; ++h) {
        float f[8];
        #pragma unroll
        for (int e = 0; e < 8; ++e)
            f[e] = (col < 8) ? Bb[(16 * h + 8 * up + e) * 8 + col] : 0.f;
        BtF[h] = split3_8(f);
    }
    // B as A-operand for B*Kg (32x8 in one K=16 tile: k=8up+e, up=1 half zero)
    Frag3 BFa;
    {
        float f[8];
        #pragma unroll
        for (int e = 0; e < 8; ++e) f[e] = up ? 0.f : Bb[col * 8 + e];
        BFa = split3_8(f);
    }
    // A and Q in C/D layout (register-resident addends)
    f32x16 afr, qfr;
    #pragma unroll
    for (int r = 0; r < 16; ++r) {
        const int row = (r & 3) + 8 * (r >> 2) + 4 * up;
        afr[r] = Ab[row * 32 + col];
        qfr[r] = Qb[row * 32 + col];
    }

    // v0 = Q * goals[:, T, :]
    if constexpr (USE_QG) {
        if (lane < 32) svv[jj] = QGb[200 * 32 + jj];
    } else {
        const float* __restrict__ gl = Gb + 200 * 32;
        float t = 0.f;
        #pragma unroll
        for (int m = 0; m < 32; ++m) t += sQ[m * 32 + jj] * gl[m];
        if (lane < 32) svv[jj] = t;
    }

    f32x16 vacc = qfr;   // V0 = Q, held in C/D layout across steps
    const float* __restrict__ qgp = USE_QG ? QGb + 199 * 32 : nullptr;

    for (int c = 0; c < NT; ++c) {
        const int step = NT - 1 - c;

        // t2 = (Q * goal_step)[jj] — one coalesced load (or fallback loop)
        float t2;
        if constexpr (USE_QG) {
            t2 = qgp[jj];
        } else {
            const float* __restrict__ grow = Gb + step * 32;
            t2 = 0.f;
            #pragma unroll
            for (int m = 0; m < 32; ++m) t2 += sQ[m * 32 + jj] * grow[m];
        }

        // ---- V (C/D regs) -> frag (B-frag layout)
        Frag3 VF[2];
        cd_to_bfrag(vacc, up, VF);

        // ---- BtV = (B^T pad) V~ (1-acc small-first), then P = V~^T A
        f32x16 bacc, pC, pB;
        #pragma unroll
        for (int r = 0; r < 16; ++r) { bacc[r] = 0.f; pC[r] = 0.f; pB[r] = 0.f; }
        bacc = mm_lo(bacc, BtF[0], VF[0]);
        bacc = mm_lo(bacc, BtF[1], VF[1]);
        bacc = mm_hh(bacc, BtF[0], VF[0]);
        bacc = mm_hh(bacc, BtF[1], VF[1]);
        pC = mm_lo(pC, VF[0], AtF[0]);
        pC = mm_lo(pC, VF[1], AtF[1]);
        pB = mm_hh(pB, VF[0], AtF[0]);
        pB = mm_hh(pB, VF[1], AtF[1]);

        // ---- btv[u] = sum_j B[j][u] * v[j] (VALU; overlaps MFMAs)
        {
            const int u = lane & 7, q8 = lane >> 3;
            const float4 v4 = *reinterpret_cast<const float4*>(&svv[4 * q8]);
            float p = 0.f;
            p += sBp[(4 * q8 + 0) * 9 + u] * v4.x;
            p += sBp[(4 * q8 + 1) * 9 + u] * v4.y;
            p += sBp[(4 * q8 + 2) * 9 + u] * v4.z;
            p += sBp[(4 * q8 + 3) * 9 + u] * v4.w;
            p += __shfl_xor(p, 8, 64);
            p += __shfl_xor(p, 16, 64);
            p += __shfl_xor(p, 32, 64);
            if (lane < 8) sbtv[u] = p;
        }

        // ---- BtV rows 0..7 -> LDS
        #pragma unroll
        for (int q = 0; q < 4; ++q)
            sBtV[(q + 4 * up) * 36 + col] = bacc[q];

        // ---- BtV as A-operand (transpose read of the LITERAL LDS BtV;
        //      rows >= 8 of the padded 32x32 are zero)
        Frag3 BtVaF[2];
        #pragma unroll
        for (int h = 0; h < 2; ++h) {
            float f[8];
            #pragma unroll
            for (int e = 0; e < 8; ++e)
                f[e] = (col < 8) ? sBtV[col * 36 + 16 * h + 8 * up + e] : 0.f;
            BtVaF[h] = split3_8(f);
        }

        // ---- M2 = BtV * A via MFMA (2-acc; B-op = AtF reused).
        //      Same literal operands as the old VALU loop — only the engine
        //      changes (error ~2^-24 rel, outside the symmetric feedback).
        f32x16 mC, mB;
        #pragma unroll
        for (int r = 0; r < 16; ++r) { mC[r] = 0.f; mB[r] = 0.f; }
        mC = mm_lo(mC, BtVaF[0], AtF[0]);
        mC = mm_lo(mC, BtVaF[1], AtF[1]);
        mB = mm_hh(mB, BtVaF[0], AtF[0]);
        mB = mm_hh(mB, BtVaF[1], AtF[1]);

        // ---- Vuu = R + BtV*B (slim fp32 loop; overlaps the M2 MFMAs)
        float cur, cur8;
        {
            float vu = rreg;
            #pragma unroll
            for (int jb = 0; jb < 8; ++jb) {
                const float4 bt4 = *reinterpret_cast<const float4*>(&sBtV[ig * 36 + 4 * jb]);
                vu += bt4.x * sBp[(4 * jb + 0) * 9 + kg];
                vu += bt4.y * sBp[(4 * jb + 1) * 9 + kg];
                vu += bt4.z * sBp[(4 * jb + 2) * 9 + kg];
                vu += bt4.w * sBp[(4 * jb + 3) * 9 + kg];
            }
            cur  = vu;
            cur8 = (ig == kg) ? 1.f : 0.f;
        }

        // ---- M2 merge -> LDS (rows q+4up; mC/mB die here, before GJ)
        #pragma unroll
        for (int q = 0; q < 4; ++q)
            sM2[(q + 4 * up) * 36 + col] = mC[q] + mB[q];

        // ---- Gauss-Jordan inverse of Vuu in registers via shfl.
        // Lane (ig,kg) holds [Vuu|I][ig][kg]. PD with diag>=1 -> no pivoting.
        #pragma unroll
        for (int p = 0; p < 8; ++p) {
            const float piv = __shfl(cur, p * 8 + p, 64);
            const float rp  = 1.0f / piv;
            const float pc  = __shfl(cur,  p * 8 + kg, 64);
            const float pc8 = __shfl(cur8, p * 8 + kg, 64);
            const float mrp = __shfl(cur,  ig * 8 + p, 64);
            const float fgj = mrp * rp;
            const bool  isp = (ig == p);
            cur  = isp ? pc  * rp : cur  - fgj * pc;
            cur8 = isp ? pc8 * rp : cur8 - fgj * pc8;
        }

        // ---- merge P, build P frag (B-frag layout; as A-op it is P^T = A^T V~)
        f32x16 pM;
        #pragma unroll
        for (int r = 0; r < 16; ++r) pM[r] = pC[r] + pB[r];
        Frag3 PF[2];
        cd_to_bfrag(pM, up, PF);

        // ---- P3: Kg = Vuu_inv * M2 ; kf = Vuu_inv * btv ; write outputs
        float* const sKg = sBtV;   // BtV dead after Vuu + BtVaF build
        {
            float ka0 = 0, ka1 = 0, ka2 = 0, ka3 = 0, kfv = 0;
            #pragma unroll
            for (int u2 = 0; u2 < 8; ++u2) {
                const float  w  = __shfl(cur8, ig * 8 + u2, 64);   // inv[ig][u2]
                const float4 m4 = *reinterpret_cast<const float4*>(&sM2[u2 * 36 + k0]);
                const float  bt = sbtv[u2];
                ka0 += w * m4.x; ka1 += w * m4.y; ka2 += w * m4.z; ka3 += w * m4.w;
                kfv += w * bt;
            }
            *reinterpret_cast<float4*>(&sKg[ig * 36 + k0]) = make_float4(ka0, ka1, ka2, ka3);
            const size_t ob = (size_t)step * NBATCH + b;
            *reinterpret_cast<float4*>(&outK[ob * 256 + ig * 32 + k0]) =
                make_float4(ka0, ka1, ka2, ka3);
            if (kg == 0) outk[ob * 8 + ig] = kfv;
        }

        // ---- Kg as B-operand (one K=16 tile: rows 8up+e; up=1 half zero)
        Frag3 KgF;
        {
            float fk[8];
            #pragma unroll
            for (int e = 0; e < 8; ++e)
                fk[e] = up ? 0.f : sKg[e * 36 + col];
            KgF = split3_8(fk);
        }

        // ---- BKg = B * Kg (emulated, 2-acc); ABK = A - BKg in fp32 (C/D regs)
        f32x16 bkC, bkB;
        #pragma unroll
        for (int r = 0; r < 16; ++r) { bkC[r] = 0.f; bkB[r] = 0.f; }
        bkC = mm_lo(bkC, BFa, KgF);
        bkB = mm_hh(bkB, BFa, KgF);
        f32x16 abk;
        #pragma unroll
        for (int r = 0; r < 16; ++r) abk[r] = afr[r] - (bkC[r] + bkB[r]);

        // ---- KF: ABK as B-frag (from registers; no LDS roundtrip)
        Frag3 KF[2];
        cd_to_bfrag(abk, up, KF);

        // ---- V' = P^T * ABK + Q (PF as A-op; 2-acc; Q added last in fp32)
        f32x16 vC, vB;
        #pragma unroll
        for (int r = 0; r < 16; ++r) { vC[r] = 0.f; vB[r] = 0.f; }
        vC = mm_lo(vC, PF[0], KF[0]);
        vC = mm_lo(vC, PF[1], KF[1]);
        vB = mm_hh(vB, PF[0], KF[0]);
        vB = mm_hh(vB, PF[1], KF[1]);

        // ---- v' = A^T v - Kg^T btv + QG (VALU; overlaps V' MFMAs)
        {
            float t1 = 0.f;
            #pragma unroll
            for (int kb = 0; kb < 8; ++kb) {
                const float4 a4 = *reinterpret_cast<const float4*>(&sAt[jj * 36 + 4 * kb]);
                const float4 v4 = *reinterpret_cast<const float4*>(&svv[4 * kb]);
                t1 += a4.x * v4.x; t1 += a4.y * v4.y;
                t1 += a4.z * v4.z; t1 += a4.w * v4.w;
            }
            float tk = 0.f;
            #pragma unroll
            for (int u = 0; u < 8; ++u) tk += sKg[u * 36 + jj] * sbtv[u];
            if (lane < 32) svv[jj] = (t1 - tk) + t2;
        }

        // ---- final merge: small terms first, Q last in fp32
        #pragma unroll
        for (int r = 0; r < 16; ++r) vacc[r] = (vC[r] + vB[r]) + qfr[r];

        if constexpr (USE_QG) qgp -= 32;
    }
}

}  // namespace

extern "C" void kernel_launch(void* const* d_in, const int* in_sizes, int n_in,
                              void* d_out, int out_size, void* d_ws, size_t ws_size,
                              hipStream_t stream) {
    const float* A = (const float*)d_in[0];
    const float* B = (const float*)d_in[1];
    const float* Q = (const float*)d_in[2];
    const float* R = (const float*)d_in[3];
    const float* G = (const float*)d_in[4];
    float* outK = (float*)d_out;
    float* outk = outK + (size_t)NT * NBATCH * 8 * 32;

    const size_t need = (size_t)NBATCH * 201 * 32 * sizeof(float);
    if (ws_size >= need) {
        float* QG = (float*)d_ws;
        qg_kernel<<<dim3(NBATCH), dim3(64), 0, stream>>>(Q, G, QG);
        lqr_kernel<true><<<dim3(NBATCH), dim3(64), 0, stream>>>(
            A, B, Q, R, G, QG, outK, outk);
    } else {
        lqr_kernel<false><<<dim3(NBATCH), dim3(64), 0, stream>>>(
            A, B, Q, R, G, nullptr, outK, outk);
    }
}

// Round 12
// 919.498 us; speedup vs baseline: 1.6762x; 1.2203x over previous
//
#include <hip/hip_runtime.h>

namespace {

constexpr int NBATCH = 2048;
constexpr int NT     = 200;

typedef _Float16 f16x8 __attribute__((ext_vector_type(8)));
typedef float    f32x16 __attribute__((ext_vector_type(16)));

struct Frag2 { f16x8 h, l; };

// Exact 2-way split of fp32 into f16 hi/lo (11-bit mantissa each, RTNE).
// r = v - h is exact in fp32 (Sterbenz); h + l represents v to ~2^-23 rel.
// Replaces the bf16 3-way split: same error class, half the MFMA products.
__device__ inline Frag2 split2_8(const float f[8]) {
  Frag2 r;
  #pragma unroll
  for (int e = 0; e < 8; ++e) {
    const float v = f[e];
    const _Float16 hH = (_Float16)v;         // RTNE
    const float r1 = v - (float)hH;          // exact
    r.h[e] = hH;
    r.l[e] = (_Float16)r1;                   // RTNE; drops ~2^-23 rel
  }
  return r;
}

// Cross-term group (lh, hl ~ 2^-11|D|) — accumulate separately from hh so
// rounding happens at ulp(2^-11|D|). Merge in fp32 VALU afterwards.
// Dropped l*l ~ 2^-22|ab| (same class as the bf16 path's dropped terms).
__device__ inline f32x16 mm_lo(f32x16 acc, const Frag2& a, const Frag2& b) {
  acc = __builtin_amdgcn_mfma_f32_32x32x16_f16(a.l, b.h, acc, 0, 0, 0);
  acc = __builtin_amdgcn_mfma_f32_32x32x16_f16(a.h, b.l, acc, 0, 0, 0);
  return acc;
}
__device__ inline f32x16 mm_hh(f32x16 acc, const Frag2& a, const Frag2& b) {
  return __builtin_amdgcn_mfma_f32_32x32x16_f16(a.h, b.h, acc, 0, 0, 0);
}

// C/D-layout regs -> B-operand Frag2 pair. One half-exchange via
// shfl_xor(32), then select + split. (R8-proven path)
__device__ inline void cd_to_bfrag(const f32x16 cd, const int up, Frag2 out[2]) {
  float sw[16];
  #pragma unroll
  for (int r = 0; r < 16; ++r) sw[r] = __shfl_xor(cd[r], 32, 64);
  #pragma unroll
  for (int h = 0; h < 2; ++h) {
    float f[8];
    const int base = 8 * h;
    #pragma unroll
    for (int e = 0; e < 4; ++e) {
      f[e]     = up ? sw[base + 4 + e] : cd[base + e];
      f[4 + e] = up ? cd[base + 4 + e] : sw[base + e];
    }
    out[h] = split2_8(f);
  }
}

// Precompute QG[b][t][j] = (Q_b * goal_t)[j] for t = 0..200.
// Same ascending-m FMA chain as the in-loop version -> bit-identical.
__global__ __launch_bounds__(64) void qg_kernel(
    const float* __restrict__ gQ, const float* __restrict__ gG,
    float* __restrict__ QG)
{
    __shared__ float sQ[1024];
    const int lane = threadIdx.x;
    const int b    = blockIdx.x;
    const float* __restrict__ Qb = gQ + (size_t)b * 1024;
    const float* __restrict__ Gb = gG + (size_t)b * (201 * 32);
    float* __restrict__ QGb = QG + (size_t)b * (201 * 32);
    #pragma unroll
    for (int m = 0; m < 4; ++m)
        reinterpret_cast<float4*>(sQ)[lane + 64 * m] =
            reinterpret_cast<const float4*>(Qb)[lane + 64 * m];
    const int jj = lane & 31, th = lane >> 5;
    for (int t = th; t < 201; t += 2) {
        const float* __restrict__ g = Gb + t * 32;
        float acc = 0.f;
        #pragma unroll
        for (int m = 0; m < 32; ++m) acc += sQ[m * 32 + jj] * g[m];
        QGb[t * 32 + jj] = acc;
    }
}

// One wave = one batch element, 200-step backward Riccati recursion.
// R4/R7-proven CONSISTENT algebra (every product consumes the same literal V~):
//   P   = V~^T A  (MFMA, VF-as-A-op) ; BtV = B^T V~ (MFMA) -> LDS
//   M2  = BtV * A (MFMA on the LITERAL LDS BtV; B-op = AtF reused)
//   Vuu = R + BtV*B (slim fp32 VALU loop) ; Kg = Vuu^-1 M2 (shfl GJ)
//   ABK = A - B*Kg (fp32 cancel FIRST)
//   V'  = P^T * ABK + Q (MFMA, PF-as-A-op = literal P^T = A^T V~)
//   v'  = A^T v - Kg^T (B^T v) + QG[step]
// MFMA 32x32x16 layouts (verified rounds 2-4; f16 same mapping as bf16):
//   A-frag: lane holds A'[l&31][16h + 8*(l>>5) + e]
//   B-frag: lane holds B'[16h + 8*(l>>5) + e][l&31]
//   C/D   : lane holds C[(r&3) + 8*(r>>2) + 4*(l>>5)][l&31]
template <bool USE_QG>
__global__ __launch_bounds__(64, 2) void lqr_kernel(
    const float* __restrict__ gA,   // [B,32,32]
    const float* __restrict__ gB,   // [B,32,8]
    const float* __restrict__ gQ,   // [B,32,32]
    const float* __restrict__ gR,   // [B,8,8]
    const float* __restrict__ gG,   // [B,201,32]
    const float* __restrict__ gQG,  // [B,201,32] precomputed Q*goal (or null)
    float* __restrict__ outK,       // [T,B,8,32]
    float* __restrict__ outk)       // [T,B,8]
{
    __shared__ __attribute__((aligned(16))) float smem[4104];
    float* const sA   = smem;          // [32][32] row-major
    float* const sQ   = smem + 1024;   // [32][32] (fallback Q*goal only)
    float* const sAt  = smem + 2048;   // [32][36] A^T, pad 36 (v' b128 rows)
    float* const sBp  = smem + 3200;   // [32][9]  B padded
    float* const sBtV = smem + 3488;   // [8][36]  B^T V ; aliased as Kg later
    float* const sM2  = smem + 3776;   // [8][36]  BtV*A
    float* const svv  = smem + 4064;   // [32] running v
    float* const sbtv = smem + 4096;   // [8]  B^T v

    const int lane = threadIdx.x;
    const int b    = blockIdx.x;
    const int ig   = lane >> 3;        // 0..7
    const int kg   = lane & 7;         // 0..7
    const int k0   = kg << 2;
    const int jj   = lane & 31;
    const int col  = lane & 31;        // MFMA col within tile
    const int up   = lane >> 5;        // 0/1: lane-half

    const float* __restrict__ Ab = gA + (size_t)b * 1024;
    const float* __restrict__ Bb = gB + (size_t)b * 256;
    const float* __restrict__ Qb = gQ + (size_t)b * 1024;
    const float* __restrict__ Gb = gG + (size_t)b * (201 * 32);
    const float* __restrict__ QGb = USE_QG ? gQG + (size_t)b * (201 * 32) : nullptr;

    // ---------------- one-time staging ----------------
    #pragma unroll
    for (int m = 0; m < 4; ++m)
        reinterpret_cast<float4*>(sA)[lane + 64 * m] =
            reinterpret_cast<const float4*>(Ab)[lane + 64 * m];
    if constexpr (!USE_QG) {
        #pragma unroll
        for (int m = 0; m < 4; ++m)
            reinterpret_cast<float4*>(sQ)[lane + 64 * m] =
                reinterpret_cast<const float4*>(Qb)[lane + 64 * m];
    }
    // A^T tile for the v' row-major b128 reads
    #pragma unroll
    for (int t = 0; t < 16; ++t) {
        const int mm = 2 * t + up;
        sAt[col * 36 + mm] = Ab[mm * 32 + col];
    }
    {
        float4 b4 = reinterpret_cast<const float4*>(Bb)[lane];
        const int fb = lane * 4;
        sBp[((fb + 0) >> 3) * 9 + ((fb + 0) & 7)] = b4.x;
        sBp[((fb + 1) >> 3) * 9 + ((fb + 1) & 7)] = b4.y;
        sBp[((fb + 2) >> 3) * 9 + ((fb + 2) & 7)] = b4.z;
        sBp[((fb + 3) >> 3) * 9 + ((fb + 3) & 7)] = b4.w;
    }
    const float rreg = gR[(size_t)b * 64 + lane];   // R[ig][kg]

    // AtF: A-frag of A^T AND B-frag of A (both read A[k][col]).
    Frag2 AtF[2];
    #pragma unroll
    for (int h = 0; h < 2; ++h) {
        float f[8];
        #pragma unroll
        for (int e = 0; e < 8; ++e) f[e] = Ab[(16 * h + 8 * up + e) * 32 + col];
        AtF[h] = split2_8(f);
    }
    // B^T zero-padded to 32x32 as A-frag
    Frag2 BtF[2];
    #pragma unroll
    for (int h = 0; h < 2; ++h) {
        float f[8];
        #pragma unroll
        for (int e = 0; e < 8; ++e)
            f[e] = (col < 8) ? Bb[(16 * h + 8 * up + e) * 8 + col] : 0.f;
        BtF[h] = split2_8(f);
    }
    // B as A-operand for B*Kg (32x8 in one K=16 tile: k=8up+e, up=1 half zero)
    Frag2 BFa;
    {
        float f[8];
        #pragma unroll
        for (int e = 0; e < 8; ++e) f[e] = up ? 0.f : Bb[col * 8 + e];
        BFa = split2_8(f);
    }
    // A and Q in C/D layout (register-resident addends)
    f32x16 afr, qfr;
    #pragma unroll
    for (int r = 0; r < 16; ++r) {
        const int row = (r & 3) + 8 * (r >> 2) + 4 * up;
        afr[r] = Ab[row * 32 + col];
        qfr[r] = Qb[row * 32 + col];
    }

    // v0 = Q * goals[:, T, :]
    if constexpr (USE_QG) {
        if (lane < 32) svv[jj] = QGb[200 * 32 + jj];
    } else {
        const float* __restrict__ gl = Gb + 200 * 32;
        float t = 0.f;
        #pragma unroll
        for (int m = 0; m < 32; ++m) t += sQ[m * 32 + jj] * gl[m];
        if (lane < 32) svv[jj] = t;
    }

    f32x16 vacc = qfr;   // V0 = Q, held in C/D layout across steps
    const float* __restrict__ qgp = USE_QG ? QGb + 199 * 32 : nullptr;

    for (int c = 0; c < NT; ++c) {
        const int step = NT - 1 - c;

        // t2 = (Q * goal_step)[jj] — one coalesced load (or fallback loop)
        float t2;
        if constexpr (USE_QG) {
            t2 = qgp[jj];
        } else {
            const float* __restrict__ grow = Gb + step * 32;
            t2 = 0.f;
            #pragma unroll
            for (int m = 0; m < 32; ++m) t2 += sQ[m * 32 + jj] * grow[m];
        }

        // ---- V (C/D regs) -> frag (B-frag layout)
        Frag2 VF[2];
        cd_to_bfrag(vacc, up, VF);

        // ---- BtV = (B^T pad) V~ (1-acc small-first), then P = V~^T A
        f32x16 bacc, pC, pB;
        #pragma unroll
        for (int r = 0; r < 16; ++r) { bacc[r] = 0.f; pC[r] = 0.f; pB[r] = 0.f; }
        bacc = mm_lo(bacc, BtF[0], VF[0]);
        bacc = mm_lo(bacc, BtF[1], VF[1]);
        bacc = mm_hh(bacc, BtF[0], VF[0]);
        bacc = mm_hh(bacc, BtF[1], VF[1]);
        pC = mm_lo(pC, VF[0], AtF[0]);
        pC = mm_lo(pC, VF[1], AtF[1]);
        pB = mm_hh(pB, VF[0], AtF[0]);
        pB = mm_hh(pB, VF[1], AtF[1]);

        // ---- btv[u] = sum_j B[j][u] * v[j] (VALU; overlaps MFMAs)
        {
            const int u = lane & 7, q8 = lane >> 3;
            const float4 v4 = *reinterpret_cast<const float4*>(&svv[4 * q8]);
            float p = 0.f;
            p += sBp[(4 * q8 + 0) * 9 + u] * v4.x;
            p += sBp[(4 * q8 + 1) * 9 + u] * v4.y;
            p += sBp[(4 * q8 + 2) * 9 + u] * v4.z;
            p += sBp[(4 * q8 + 3) * 9 + u] * v4.w;
            p += __shfl_xor(p, 8, 64);
            p += __shfl_xor(p, 16, 64);
            p += __shfl_xor(p, 32, 64);
            if (lane < 8) sbtv[u] = p;
        }

        // ---- BtV rows 0..7 -> LDS
        #pragma unroll
        for (int q = 0; q < 4; ++q)
            sBtV[(q + 4 * up) * 36 + col] = bacc[q];

        // ---- BtV as A-operand (transpose read of the LITERAL LDS BtV;
        //      rows >= 8 of the padded 32x32 are zero)
        Frag2 BtVaF[2];
        #pragma unroll
        for (int h = 0; h < 2; ++h) {
            float f[8];
            #pragma unroll
            for (int e = 0; e < 8; ++e)
                f[e] = (col < 8) ? sBtV[col * 36 + 16 * h + 8 * up + e] : 0.f;
            BtVaF[h] = split2_8(f);
        }

        // ---- M2 = BtV * A via MFMA (2-acc; B-op = AtF reused).
        f32x16 mC, mB;
        #pragma unroll
        for (int r = 0; r < 16; ++r) { mC[r] = 0.f; mB[r] = 0.f; }
        mC = mm_lo(mC, BtVaF[0], AtF[0]);
        mC = mm_lo(mC, BtVaF[1], AtF[1]);
        mB = mm_hh(mB, BtVaF[0], AtF[0]);
        mB = mm_hh(mB, BtVaF[1], AtF[1]);

        // ---- Vuu = R + BtV*B (slim fp32 loop; overlaps the M2 MFMAs)
        float cur, cur8;
        {
            float vu = rreg;
            #pragma unroll
            for (int jb = 0; jb < 8; ++jb) {
                const float4 bt4 = *reinterpret_cast<const float4*>(&sBtV[ig * 36 + 4 * jb]);
                vu += bt4.x * sBp[(4 * jb + 0) * 9 + kg];
                vu += bt4.y * sBp[(4 * jb + 1) * 9 + kg];
                vu += bt4.z * sBp[(4 * jb + 2) * 9 + kg];
                vu += bt4.w * sBp[(4 * jb + 3) * 9 + kg];
            }
            cur  = vu;
            cur8 = (ig == kg) ? 1.f : 0.f;
        }

        // ---- M2 merge -> LDS (rows q+4up; mC/mB die here, before GJ)
        #pragma unroll
        for (int q = 0; q < 4; ++q)
            sM2[(q + 4 * up) * 36 + col] = mC[q] + mB[q];

        // ---- Gauss-Jordan inverse of Vuu in registers via shfl.
        // Lane (ig,kg) holds [Vuu|I][ig][kg]. PD with diag>=1 -> no pivoting.
        #pragma unroll
        for (int p = 0; p < 8; ++p) {
            const float piv = __shfl(cur, p * 8 + p, 64);
            const float rp  = 1.0f / piv;
            const float pc  = __shfl(cur,  p * 8 + kg, 64);
            const float pc8 = __shfl(cur8, p * 8 + kg, 64);
            const float mrp = __shfl(cur,  ig * 8 + p, 64);
            const float fgj = mrp * rp;
            const bool  isp = (ig == p);
            cur  = isp ? pc  * rp : cur  - fgj * pc;
            cur8 = isp ? pc8 * rp : cur8 - fgj * pc8;
        }

        // ---- merge P, build P frag (B-frag layout; as A-op it is P^T = A^T V~)
        f32x16 pM;
        #pragma unroll
        for (int r = 0; r < 16; ++r) pM[r] = pC[r] + pB[r];
        Frag2 PF[2];
        cd_to_bfrag(pM, up, PF);

        // ---- P3: Kg = Vuu_inv * M2 ; kf = Vuu_inv * btv ; write outputs
        float* const sKg = sBtV;   // BtV dead after Vuu + BtVaF build
        {
            float ka0 = 0, ka1 = 0, ka2 = 0, ka3 = 0, kfv = 0;
            #pragma unroll
            for (int u2 = 0; u2 < 8; ++u2) {
                const float  w  = __shfl(cur8, ig * 8 + u2, 64);   // inv[ig][u2]
                const float4 m4 = *reinterpret_cast<const float4*>(&sM2[u2 * 36 + k0]);
                const float  bt = sbtv[u2];
                ka0 += w * m4.x; ka1 += w * m4.y; ka2 += w * m4.z; ka3 += w * m4.w;
                kfv += w * bt;
            }
            *reinterpret_cast<float4*>(&sKg[ig * 36 + k0]) = make_float4(ka0, ka1, ka2, ka3);
            const size_t ob = (size_t)step * NBATCH + b;
            *reinterpret_cast<float4*>(&outK[ob * 256 + ig * 32 + k0]) =
                make_float4(ka0, ka1, ka2, ka3);
            if (kg == 0) outk[ob * 8 + ig] = kfv;
        }

        // ---- Kg as B-operand (one K=16 tile: rows 8up+e; up=1 half zero)
        Frag2 KgF;
        {
            float fk[8];
            #pragma unroll
            for (int e = 0; e < 8; ++e)
                fk[e] = up ? 0.f : sKg[e * 36 + col];
            KgF = split2_8(fk);
        }

        // ---- BKg = B * Kg (emulated, 2-acc); ABK = A - BKg in fp32 (C/D regs)
        f32x16 bkC, bkB;
        #pragma unroll
        for (int r = 0; r < 16; ++r) { bkC[r] = 0.f; bkB[r] = 0.f; }
        bkC = mm_lo(bkC, BFa, KgF);
        bkB = mm_hh(bkB, BFa, KgF);
        f32x16 abk;
        #pragma unroll
        for (int r = 0; r < 16; ++r) abk[r] = afr[r] - (bkC[r] + bkB[r]);

        // ---- KF: ABK as B-frag (from registers; no LDS roundtrip)
        Frag2 KF[2];
        cd_to_bfrag(abk, up, KF);

        // ---- V' = P^T * ABK + Q (PF as A-op; 2-acc; Q added last in fp32)
        f32x16 vC, vB;
        #pragma unroll
        for (int r = 0; r < 16; ++r) { vC[r] = 0.f; vB[r] = 0.f; }
        vC = mm_lo(vC, PF[0], KF[0]);
        vC = mm_lo(vC, PF[1], KF[1]);
        vB = mm_hh(vB, PF[0], KF[0]);
        vB = mm_hh(vB, PF[1], KF[1]);

        // ---- v' = A^T v - Kg^T btv + QG (VALU; overlaps V' MFMAs)
        {
            float t1 = 0.f;
            #pragma unroll
            for (int kb = 0; kb < 8; ++kb) {
                const float4 a4 = *reinterpret_cast<const float4*>(&sAt[jj * 36 + 4 * kb]);
                const float4 v4 = *reinterpret_cast<const float4*>(&svv[4 * kb]);
                t1 += a4.x * v4.x; t1 += a4.y * v4.y;
                t1 += a4.z * v4.z; t1 += a4.w * v4.w;
            }
            float tk = 0.f;
            #pragma unroll
            for (int u = 0; u < 8; ++u) tk += sKg[u * 36 + jj] * sbtv[u];
            if (lane < 32) svv[jj] = (t1 - tk) + t2;
        }

        // ---- final merge: small terms first, Q last in fp32
        #pragma unroll
        for (int r = 0; r < 16; ++r) vacc[r] = (vC[r] + vB[r]) + qfr[r];

        if constexpr (USE_QG) qgp -= 32;
    }
}

}  // namespace

extern "C" void kernel_launch(void* const* d_in, const int* in_sizes, int n_in,
                              void* d_out, int out_size, void* d_ws, size_t ws_size,
                              hipStream_t stream) {
    const float* A = (const float*)d_in[0];
    const float* B = (const float*)d_in[1];
    const float* Q = (const float*)d_in[2];
    const float* R = (const float*)d_in[3];
    const float* G = (const float*)d_in[4];
    float* outK = (float*)d_out;
    float* outk = outK + (size_t)NT * NBATCH * 8 * 32;

    const size_t need = (size_t)NBATCH * 201 * 32 * sizeof(float);
    if (ws_size >= need) {
        float* QG = (float*)d_ws;
        qg_kernel<<<dim3(NBATCH), dim3(64), 0, stream>>>(Q, G, QG);
        lqr_kernel<true><<<dim3(NBATCH), dim3(64), 0, stream>>>(
            A, B, Q, R, G, QG, outK, outk);
    } else {
        lqr_kernel<false><<<dim3(NBATCH), dim3(64), 0, stream>>>(
            A, B, Q, R, G, nullptr, outK, outk);
    }
}

// Round 13
// 790.934 us; speedup vs baseline: 1.9486x; 1.1625x over previous
//
#include <hip/hip_runtime.h>

namespace {

constexpr int NBATCH = 2048;
constexpr int NT     = 200;

typedef _Float16 f16x8 __attribute__((ext_vector_type(8)));
typedef float    f32x16 __attribute__((ext_vector_type(16)));
typedef int      i32x2  __attribute__((ext_vector_type(2)));

struct Frag2 { f16x8 h, l; };

// Exact 2-way split of fp32 into f16 hi/lo (11-bit mantissa each, RTNE).
// r = v - h is exact in fp32 (Sterbenz); h + l represents v to ~2^-23 rel.
__device__ inline Frag2 split2_8(const float f[8]) {
  Frag2 r;
  #pragma unroll
  for (int e = 0; e < 8; ++e) {
    const float v = f[e];
    const _Float16 hH = (_Float16)v;         // RTNE
    const float r1 = v - (float)hH;          // exact
    r.h[e] = hH;
    r.l[e] = (_Float16)r1;                   // RTNE; drops ~2^-23 rel
  }
  return r;
}

// Cross-term group (lh, hl ~ 2^-11|D|) — accumulate separately from hh so
// rounding happens at ulp(2^-11|D|). Merge in fp32 VALU afterwards.
__device__ inline f32x16 mm_lo(f32x16 acc, const Frag2& a, const Frag2& b) {
  acc = __builtin_amdgcn_mfma_f32_32x32x16_f16(a.l, b.h, acc, 0, 0, 0);
  acc = __builtin_amdgcn_mfma_f32_32x32x16_f16(a.h, b.l, acc, 0, 0, 0);
  return acc;
}
__device__ inline f32x16 mm_hh(f32x16 acc, const Frag2& a, const Frag2& b) {
  return __builtin_amdgcn_mfma_f32_32x32x16_f16(a.h, b.h, acc, 0, 0, 0);
}

// v_permlane32_swap_b32: out0 = {a.lanes0-31, b.lanes0-31},
//                        out1 = {a.lanes32-63, b.lanes32-63}.
// Semantics hardware-verified in round 9 (bit-identical pass).
__device__ inline void half_swap(float a, float b, float& oa, float& ob) {
  i32x2 r = __builtin_amdgcn_permlane32_swap(
      __float_as_int(a), __float_as_int(b), false, false);
  oa = __int_as_float(r[0]);
  ob = __int_as_float(r[1]);
}

// C/D-layout regs -> B-operand Frag2 pair, all-VALU via permlane32_swap.
// out0 of half_swap(cd[base+e], cd[base+4+e]) == f[e] (lower: own cd[base+e];
// upper: lower-half's cd[base+4+e]); out1 == f[4+e]. Replaces 16 ds_bpermute
// + 16 cndmask per call with 8 permlanes, zero added live state.
__device__ inline void cd_to_bfrag(const f32x16 cd, Frag2 out[2]) {
  #pragma unroll
  for (int h = 0; h < 2; ++h) {
    float f[8];
    const int base = 8 * h;
    #pragma unroll
    for (int e = 0; e < 4; ++e)
      half_swap(cd[base + e], cd[base + 4 + e], f[e], f[4 + e]);
    out[h] = split2_8(f);
  }
}

// Precompute QG[b][t][j] = (Q_b * goal_t)[j] for t = 0..200.
// Same ascending-m FMA chain as the in-loop version -> bit-identical.
__global__ __launch_bounds__(64) void qg_kernel(
    const float* __restrict__ gQ, const float* __restrict__ gG,
    float* __restrict__ QG)
{
    __shared__ float sQ[1024];
    const int lane = threadIdx.x;
    const int b    = blockIdx.x;
    const float* __restrict__ Qb = gQ + (size_t)b * 1024;
    const float* __restrict__ Gb = gG + (size_t)b * (201 * 32);
    float* __restrict__ QGb = QG + (size_t)b * (201 * 32);
    #pragma unroll
    for (int m = 0; m < 4; ++m)
        reinterpret_cast<float4*>(sQ)[lane + 64 * m] =
            reinterpret_cast<const float4*>(Qb)[lane + 64 * m];
    const int jj = lane & 31, th = lane >> 5;
    for (int t = th; t < 201; t += 2) {
        const float* __restrict__ g = Gb + t * 32;
        float acc = 0.f;
        #pragma unroll
        for (int m = 0; m < 32; ++m) acc += sQ[m * 32 + jj] * g[m];
        QGb[t * 32 + jj] = acc;
    }
}

// One wave = one batch element, 200-step backward Riccati recursion.
// R4/R7-proven CONSISTENT algebra (every product consumes the same literal V~):
//   P   = V~^T A  (MFMA, VF-as-A-op) ; BtV = B^T V~ (MFMA) -> LDS
//   M2  = BtV * A (MFMA on the LITERAL LDS BtV; B-op = AtF reused)
//   Vuu = R + BtV*B (slim fp32 VALU loop) ; Kg = Vuu^-1 M2 (shfl GJ)
//   ABK = A - B*Kg (fp32 cancel FIRST)
//   V'  = P^T * ABK + Q (MFMA, PF-as-A-op = literal P^T = A^T V~)
//   v'  = A^T v - Kg^T (B^T v) + QG[step]
// MFMA 32x32x16 layouts (verified rounds 2-4; f16 same mapping as bf16):
//   A-frag: lane holds A'[l&31][16h + 8*(l>>5) + e]
//   B-frag: lane holds B'[16h + 8*(l>>5) + e][l&31]
//   C/D   : lane holds C[(r&3) + 8*(r>>2) + 4*(l>>5)][l&31]
template <bool USE_QG>
__global__ __launch_bounds__(64, 2) void lqr_kernel(
    const float* __restrict__ gA,   // [B,32,32]
    const float* __restrict__ gB,   // [B,32,8]
    const float* __restrict__ gQ,   // [B,32,32]
    const float* __restrict__ gR,   // [B,8,8]
    const float* __restrict__ gG,   // [B,201,32]
    const float* __restrict__ gQG,  // [B,201,32] precomputed Q*goal (or null)
    float* __restrict__ outK,       // [T,B,8,32]
    float* __restrict__ outk)       // [T,B,8]
{
    __shared__ __attribute__((aligned(16))) float smem[4104];
    float* const sA   = smem;          // [32][32] row-major
    float* const sQ   = smem + 1024;   // [32][32] (fallback Q*goal only)
    float* const sAt  = smem + 2048;   // [32][36] A^T, pad 36 (v' b128 rows)
    float* const sBp  = smem + 3200;   // [32][9]  B padded
    float* const sBtV = smem + 3488;   // [8][36]  B^T V ; aliased as Kg later
    float* const sM2  = smem + 3776;   // [8][36]  BtV*A
    float* const svv  = smem + 4064;   // [32] running v
    float* const sbtv = smem + 4096;   // [8]  B^T v

    const int lane = threadIdx.x;
    const int b    = blockIdx.x;
    const int ig   = lane >> 3;        // 0..7
    const int kg   = lane & 7;         // 0..7
    const int k0   = kg << 2;
    const int jj   = lane & 31;
    const int col  = lane & 31;        // MFMA col within tile
    const int up   = lane >> 5;        // 0/1: lane-half

    const float* __restrict__ Ab = gA + (size_t)b * 1024;
    const float* __restrict__ Bb = gB + (size_t)b * 256;
    const float* __restrict__ Qb = gQ + (size_t)b * 1024;
    const float* __restrict__ Gb = gG + (size_t)b * (201 * 32);
    const float* __restrict__ QGb = USE_QG ? gQG + (size_t)b * (201 * 32) : nullptr;

    // ---------------- one-time staging ----------------
    #pragma unroll
    for (int m = 0; m < 4; ++m)
        reinterpret_cast<float4*>(sA)[lane + 64 * m] =
            reinterpret_cast<const float4*>(Ab)[lane + 64 * m];
    if constexpr (!USE_QG) {
        #pragma unroll
        for (int m = 0; m < 4; ++m)
            reinterpret_cast<float4*>(sQ)[lane + 64 * m] =
                reinterpret_cast<const float4*>(Qb)[lane + 64 * m];
    }
    // A^T tile for the v' row-major b128 reads
    #pragma unroll
    for (int t = 0; t < 16; ++t) {
        const int mm = 2 * t + up;
        sAt[col * 36 + mm] = Ab[mm * 32 + col];
    }
    {
        float4 b4 = reinterpret_cast<const float4*>(Bb)[lane];
        const int fb = lane * 4;
        sBp[((fb + 0) >> 3) * 9 + ((fb + 0) & 7)] = b4.x;
        sBp[((fb + 1) >> 3) * 9 + ((fb + 1) & 7)] = b4.y;
        sBp[((fb + 2) >> 3) * 9 + ((fb + 2) & 7)] = b4.z;
        sBp[((fb + 3) >> 3) * 9 + ((fb + 3) & 7)] = b4.w;
    }
    const float rreg = gR[(size_t)b * 64 + lane];   // R[ig][kg]

    // AtF: A-frag of A^T AND B-frag of A (both read A[k][col]).
    Frag2 AtF[2];
    #pragma unroll
    for (int h = 0; h < 2; ++h) {
        float f[8];
        #pragma unroll
        for (int e = 0; e < 8; ++e) f[e] = Ab[(16 * h + 8 * up + e) * 32 + col];
        AtF[h] = split2_8(f);
    }
    // B^T zero-padded to 32x32 as A-frag
    Frag2 BtF[2];
    #pragma unroll
    for (int h = 0; h < 2; ++h) {
        float f[8];
        #pragma unroll
        for (int e = 0; e < 8; ++e)
            f[e] = (col < 8) ? Bb[(16 * h + 8 * up + e) * 8 + col] : 0.f;
        BtF[h] = split2_8(f);
    }
    // B as A-operand for B*Kg (32x8 in one K=16 tile: k=8up+e, up=1 half zero)
    Frag2 BFa;
    {
        float f[8];
        #pragma unroll
        for (int e = 0; e < 8; ++e) f[e] = up ? 0.f : Bb[col * 8 + e];
        BFa = split2_8(f);
    }
    // A and Q in C/D layout (register-resident addends)
    f32x16 afr, qfr;
    #pragma unroll
    for (int r = 0; r < 16; ++r) {
        const int row = (r & 3) + 8 * (r >> 2) + 4 * up;
        afr[r] = Ab[row * 32 + col];
        qfr[r] = Qb[row * 32 + col];
    }

    // v0 = Q * goals[:, T, :]
    if constexpr (USE_QG) {
        if (lane < 32) svv[jj] = QGb[200 * 32 + jj];
    } else {
        const float* __restrict__ gl = Gb + 200 * 32;
        float t = 0.f;
        #pragma unroll
        for (int m = 0; m < 32; ++m) t += sQ[m * 32 + jj] * gl[m];
        if (lane < 32) svv[jj] = t;
    }

    f32x16 vacc = qfr;   // V0 = Q, held in C/D layout across steps
    const float* __restrict__ qgp = USE_QG ? QGb + 199 * 32 : nullptr;

    for (int c = 0; c < NT; ++c) {
        const int step = NT - 1 - c;

        // t2 = (Q * goal_step)[jj] — one coalesced load (or fallback loop)
        float t2;
        if constexpr (USE_QG) {
            t2 = qgp[jj];
        } else {
            const float* __restrict__ grow = Gb + step * 32;
            t2 = 0.f;
            #pragma unroll
            for (int m = 0; m < 32; ++m) t2 += sQ[m * 32 + jj] * grow[m];
        }

        // ---- V (C/D regs) -> frag (B-frag layout), all-VALU permlane path
        Frag2 VF[2];
        cd_to_bfrag(vacc, VF);

        // ---- BtV = (B^T pad) V~ (1-acc small-first), then P = V~^T A
        f32x16 bacc, pC, pB;
        #pragma unroll
        for (int r = 0; r < 16; ++r) { bacc[r] = 0.f; pC[r] = 0.f; pB[r] = 0.f; }
        bacc = mm_lo(bacc, BtF[0], VF[0]);
        bacc = mm_lo(bacc, BtF[1], VF[1]);
        bacc = mm_hh(bacc, BtF[0], VF[0]);
        bacc = mm_hh(bacc, BtF[1], VF[1]);
        pC = mm_lo(pC, VF[0], AtF[0]);
        pC = mm_lo(pC, VF[1], AtF[1]);
        pB = mm_hh(pB, VF[0], AtF[0]);
        pB = mm_hh(pB, VF[1], AtF[1]);

        // ---- btv[u] = sum_j B[j][u] * v[j] (VALU; overlaps MFMAs)
        {
            const int u = lane & 7, q8 = lane >> 3;
            const float4 v4 = *reinterpret_cast<const float4*>(&svv[4 * q8]);
            float p = 0.f;
            p += sBp[(4 * q8 + 0) * 9 + u] * v4.x;
            p += sBp[(4 * q8 + 1) * 9 + u] * v4.y;
            p += sBp[(4 * q8 + 2) * 9 + u] * v4.z;
            p += sBp[(4 * q8 + 3) * 9 + u] * v4.w;
            p += __shfl_xor(p, 8, 64);
            p += __shfl_xor(p, 16, 64);
            p += __shfl_xor(p, 32, 64);
            if (lane < 8) sbtv[u] = p;
        }

        // ---- BtV rows 0..7 -> LDS
        #pragma unroll
        for (int q = 0; q < 4; ++q)
            sBtV[(q + 4 * up) * 36 + col] = bacc[q];

        // ---- BtV as A-operand (transpose read of the LITERAL LDS BtV;
        //      rows >= 8 of the padded 32x32 are zero)
        Frag2 BtVaF[2];
        #pragma unroll
        for (int h = 0; h < 2; ++h) {
            float f[8];
            #pragma unroll
            for (int e = 0; e < 8; ++e)
                f[e] = (col < 8) ? sBtV[col * 36 + 16 * h + 8 * up + e] : 0.f;
            BtVaF[h] = split2_8(f);
        }

        // ---- M2 = BtV * A via MFMA (2-acc; B-op = AtF reused).
        f32x16 mC, mB;
        #pragma unroll
        for (int r = 0; r < 16; ++r) { mC[r] = 0.f; mB[r] = 0.f; }
        mC = mm_lo(mC, BtVaF[0], AtF[0]);
        mC = mm_lo(mC, BtVaF[1], AtF[1]);
        mB = mm_hh(mB, BtVaF[0], AtF[0]);
        mB = mm_hh(mB, BtVaF[1], AtF[1]);

        // ---- Vuu = R + BtV*B (slim fp32 loop; overlaps the M2 MFMAs)
        float cur, cur8;
        {
            float vu = rreg;
            #pragma unroll
            for (int jb = 0; jb < 8; ++jb) {
                const float4 bt4 = *reinterpret_cast<const float4*>(&sBtV[ig * 36 + 4 * jb]);
                vu += bt4.x * sBp[(4 * jb + 0) * 9 + kg];
                vu += bt4.y * sBp[(4 * jb + 1) * 9 + kg];
                vu += bt4.z * sBp[(4 * jb + 2) * 9 + kg];
                vu += bt4.w * sBp[(4 * jb + 3) * 9 + kg];
            }
            cur  = vu;
            cur8 = (ig == kg) ? 1.f : 0.f;
        }

        // ---- M2 merge -> LDS (rows q+4up; mC/mB die here, before GJ)
        #pragma unroll
        for (int q = 0; q < 4; ++q)
            sM2[(q + 4 * up) * 36 + col] = mC[q] + mB[q];

        // ---- Gauss-Jordan inverse of Vuu in registers via shfl.
        // Lane (ig,kg) holds [Vuu|I][ig][kg]. PD with diag>=1 -> no pivoting.
        #pragma unroll
        for (int p = 0; p < 8; ++p) {
            const float piv = __shfl(cur, p * 8 + p, 64);
            const float rp  = 1.0f / piv;
            const float pc  = __shfl(cur,  p * 8 + kg, 64);
            const float pc8 = __shfl(cur8, p * 8 + kg, 64);
            const float mrp = __shfl(cur,  ig * 8 + p, 64);
            const float fgj = mrp * rp;
            const bool  isp = (ig == p);
            cur  = isp ? pc  * rp : cur  - fgj * pc;
            cur8 = isp ? pc8 * rp : cur8 - fgj * pc8;
        }

        // ---- merge P, build P frag (B-frag layout; as A-op it is P^T = A^T V~)
        f32x16 pM;
        #pragma unroll
        for (int r = 0; r < 16; ++r) pM[r] = pC[r] + pB[r];
        Frag2 PF[2];
        cd_to_bfrag(pM, PF);

        // ---- P3: Kg = Vuu_inv * M2 ; kf = Vuu_inv * btv ; write outputs
        float* const sKg = sBtV;   // BtV dead after Vuu + BtVaF build
        {
            float ka0 = 0, ka1 = 0, ka2 = 0, ka3 = 0, kfv = 0;
            #pragma unroll
            for (int u2 = 0; u2 < 8; ++u2) {
                const float  w  = __shfl(cur8, ig * 8 + u2, 64);   // inv[ig][u2]
                const float4 m4 = *reinterpret_cast<const float4*>(&sM2[u2 * 36 + k0]);
                const float  bt = sbtv[u2];
                ka0 += w * m4.x; ka1 += w * m4.y; ka2 += w * m4.z; ka3 += w * m4.w;
                kfv += w * bt;
            }
            *reinterpret_cast<float4*>(&sKg[ig * 36 + k0]) = make_float4(ka0, ka1, ka2, ka3);
            const size_t ob = (size_t)step * NBATCH + b;
            *reinterpret_cast<float4*>(&outK[ob * 256 + ig * 32 + k0]) =
                make_float4(ka0, ka1, ka2, ka3);
            if (kg == 0) outk[ob * 8 + ig] = kfv;
        }

        // ---- Kg as B-operand (one K=16 tile: rows 8up+e; up=1 half zero)
        Frag2 KgF;
        {
            float fk[8];
            #pragma unroll
            for (int e = 0; e < 8; ++e)
                fk[e] = up ? 0.f : sKg[e * 36 + col];
            KgF = split2_8(fk);
        }

        // ---- BKg = B * Kg (emulated, 2-acc); ABK = A - BKg in fp32 (C/D regs)
        f32x16 bkC, bkB;
        #pragma unroll
        for (int r = 0; r < 16; ++r) { bkC[r] = 0.f; bkB[r] = 0.f; }
        bkC = mm_lo(bkC, BFa, KgF);
        bkB = mm_hh(bkB, BFa, KgF);
        f32x16 abk;
        #pragma unroll
        for (int r = 0; r < 16; ++r) abk[r] = afr[r] - (bkC[r] + bkB[r]);

        // ---- KF: ABK as B-frag (from registers; no LDS roundtrip)
        Frag2 KF[2];
        cd_to_bfrag(abk, KF);

        // ---- V' = P^T * ABK + Q (PF as A-op; 2-acc; Q added last in fp32)
        f32x16 vC, vB;
        #pragma unroll
        for (int r = 0; r < 16; ++r) { vC[r] = 0.f; vB[r] = 0.f; }
        vC = mm_lo(vC, PF[0], KF[0]);
        vC = mm_lo(vC, PF[1], KF[1]);
        vB = mm_hh(vB, PF[0], KF[0]);
        vB = mm_hh(vB, PF[1], KF[1]);

        // ---- v' = A^T v - Kg^T btv + QG (VALU; overlaps V' MFMAs)
        {
            float t1 = 0.f;
            #pragma unroll
            for (int kb = 0; kb < 8; ++kb) {
                const float4 a4 = *reinterpret_cast<const float4*>(&sAt[jj * 36 + 4 * kb]);
                const float4 v4 = *reinterpret_cast<const float4*>(&svv[4 * kb]);
                t1 += a4.x * v4.x; t1 += a4.y * v4.y;
                t1 += a4.z * v4.z; t1 += a4.w * v4.w;
            }
            float tk = 0.f;
            #pragma unroll
            for (int u = 0; u < 8; ++u) tk += sKg[u * 36 + jj] * sbtv[u];
            if (lane < 32) svv[jj] = (t1 - tk) + t2;
        }

        // ---- final merge: small terms first, Q last in fp32
        #pragma unroll
        for (int r = 0; r < 16; ++r) vacc[r] = (vC[r] + vB[r]) + qfr[r];

        if constexpr (USE_QG) qgp -= 32;
    }
}

}  // namespace

extern "C" void kernel_launch(void* const* d_in, const int* in_sizes, int n_in,
                              void* d_out, int out_size, void* d_ws, size_t ws_size,
                              hipStream_t stream) {
    const float* A = (const float*)d_in[0];
    const float* B = (const float*)d_in[1];
    const float* Q = (const float*)d_in[2];
    const float* R = (const float*)d_in[3];
    const float* G = (const float*)d_in[4];
    float* outK = (float*)d_out;
    float* outk = outK + (size_t)NT * NBATCH * 8 * 32;

    const size_t need = (size_t)NBATCH * 201 * 32 * sizeof(float);
    if (ws_size >= need) {
        float* QG = (float*)d_ws;
        qg_kernel<<<dim3(NBATCH), dim3(64), 0, stream>>>(Q, G, QG);
        lqr_kernel<true><<<dim3(NBATCH), dim3(64), 0, stream>>>(
            A, B, Q, R, G, QG, outK, outk);
    } else {
        lqr_kernel<false><<<dim3(NBATCH), dim3(64), 0, stream>>>(
            A, B, Q, R, G, nullptr, outK, outk);
    }
}